// Round 8
// baseline (391.468 us; speedup 1.0000x reference)
//
#include <hip/hip_runtime.h>

// EdgeModel: out = relu(x@W1+b1)@W2 + b2 + x, x = [src|dest|ea|u[batch]].
// E=1e6, dims 128. bf16 MFMA 16x16x32, fp32 accum.
// R8: DS-pipe offload. GEMM1 B-frags + residual read DIRECT FROM GLOBAL
// (L1/L2-warm; ks maps 1:1 to source arrays so concat is free). x never
// touches LDS -> bar1 gone. h double-buffered in LDS -> 1 barrier/tile.
// Next-tile warmed with touch-loads (asm keepalive). (256,2): forced
// occupancy (R6/R7) spills -- footprint is ~220 unified regs.

#define E_TOTAL   1000000
#define TILE_M    64
#define NUM_TILES (E_TOTAL / TILE_M)   // 15625
#define GRID      2048

typedef __attribute__((ext_vector_type(8))) __bf16 bf16x8;
typedef __attribute__((ext_vector_type(4))) __bf16 bf16x4;
typedef __attribute__((ext_vector_type(4))) float  f32x4;

__device__ inline bf16x8 pack8(f32x4 v0, f32x4 v1) {
    bf16x8 r;
    r[0] = (__bf16)v0[0]; r[1] = (__bf16)v0[1];
    r[2] = (__bf16)v0[2]; r[3] = (__bf16)v0[3];
    r[4] = (__bf16)v1[0]; r[5] = (__bf16)v1[1];
    r[6] = (__bf16)v1[2]; r[7] = (__bf16)v1[3];
    return r;
}

// row-major [64][128] bf16, 16 groups of 8/row, group XOR (row&15):
// all b128 reads conflict-free.
__device__ inline int swz(int row, int group) {
    return (row * 16 + (group ^ (row & 15))) * 8;
}

__global__ __launch_bounds__(256, 2)
void edge_mlp(const float* __restrict__ gsrc,
              const float* __restrict__ gdst,
              const float* __restrict__ gea,
              const float* __restrict__ gu,
              const int*   __restrict__ gbatch,
              const float* __restrict__ gw1,
              const float* __restrict__ gb1,
              const float* __restrict__ gw2,
              const float* __restrict__ gb2,
              float* __restrict__ gout)
{
    __shared__ __align__(16) __bf16 hl[2][TILE_M * 128];   // h, double-buffered

    const int tid  = threadIdx.x;
    const int lane = tid & 63;
    const int wid  = tid >> 6;     // wave owns hidden/out-dim rows [wb,wb+32)
    const int l15  = lane & 15;
    const int g    = lane >> 4;
    const int wb   = wid * 32;

    // ---- W1^T and W2^T as A-fragments:
    //      lane holds W^T[row = wb+m*16+l15][k = ks*32+g*8+j] = gw[k*128+row]
    bf16x8 w1t[2][4], w2t[2][4];
#pragma unroll
    for (int m = 0; m < 2; ++m)
#pragma unroll
        for (int ks = 0; ks < 4; ++ks) {
            bf16x8 t1, t2;
#pragma unroll
            for (int j = 0; j < 8; ++j) {
                const int k = ks * 32 + g * 8 + j;
                const int r = wb + m * 16 + l15;
                t1[j] = (__bf16)gw1[k * 128 + r];
                t2[j] = (__bf16)gw2[k * 128 + r];
            }
            w1t[m][ks] = t1;
            w2t[m][ks] = t2;
        }

    // ---- biases along C rows: b[wb + m*16 + g*4 + r]
    f32x4 b1v[2], b2v[2];
#pragma unroll
    for (int m = 0; m < 2; ++m)
#pragma unroll
        for (int r = 0; r < 4; ++r) {
            b1v[m][r] = gb1[wb + m * 16 + g * 4 + r];
            b2v[m][r] = gb2[wb + m * 16 + g * 4 + r];
        }

    const float* const arr3[3] = {gsrc, gdst, gea};
    // residual source for this wave's dims [wb,wb+32): exactly one array
    const float* rp = (wid == 0) ? gsrc : (wid == 1) ? gdst
                    : (wid == 2) ? gea  : gu;

    int tile = blockIdx.x;
    int p = 0;

    while (true) {
        const int e0 = tile * TILE_M;

        // ---- batch indices for this tile's 4 edge groups (L2-warm) ----
        int bt[4];
#pragma unroll
        for (int n = 0; n < 4; ++n)
            bt[n] = gbatch[e0 + n * 16 + l15];

        // ---- warm next tile into L2 (touch loads; line-granular) ----
        const int  nxt  = tile + GRID;
        const bool have = nxt < NUM_TILES;
        float wv0 = 0.f, wv1 = 0.f, wv2 = 0.f;
        int   wv3 = 0;
        if (have) {
            const int    en = nxt * TILE_M + (tid >> 2);
            const size_t o  = (size_t)en * 32 + (tid & 3) * 8;
            wv0 = gsrc[o];
            wv1 = gdst[o];
            wv2 = gea[o];
            wv3 = gbatch[en];
        }

        // ---- GEMM1^T: h^T = W1^T @ x^T + b1 (B-frags direct from global,
        //      2-stage ks pipeline; ks == source array) ----
        f32x4 acc[2][4];
#pragma unroll
        for (int m = 0; m < 2; ++m)
#pragma unroll
            for (int n = 0; n < 4; ++n)
                acc[m][n] = b1v[m];

        f32x4 ch[2][8];   // [stage][n*2+half], 8 fp32 per (n)
#pragma unroll
        for (int n = 0; n < 4; ++n) {
            const float* q = gsrc + (size_t)(e0 + n * 16 + l15) * 32 + g * 8;
            ch[0][n * 2]     = *(const f32x4*)q;
            ch[0][n * 2 + 1] = *(const f32x4*)(q + 4);
        }
#pragma unroll
        for (int ks = 0; ks < 4; ++ks) {
            if (ks < 3) {
                const int kn = ks + 1;
#pragma unroll
                for (int n = 0; n < 4; ++n) {
                    const float* q = (kn < 3)
                        ? (arr3[kn] + (size_t)(e0 + n * 16 + l15) * 32 + g * 8)
                        : (gu + (size_t)bt[n] * 32 + g * 8);
                    ch[kn & 1][n * 2]     = *(const f32x4*)q;
                    ch[kn & 1][n * 2 + 1] = *(const f32x4*)(q + 4);
                }
            }
            bf16x8 bf[4];
#pragma unroll
            for (int n = 0; n < 4; ++n)
                bf[n] = pack8(ch[ks & 1][n * 2], ch[ks & 1][n * 2 + 1]);
#pragma unroll
            for (int m = 0; m < 2; ++m)
#pragma unroll
                for (int n = 0; n < 4; ++n)
                    acc[m][n] = __builtin_amdgcn_mfma_f32_16x16x32_bf16(
                        w1t[m][ks], bf[n], acc[m][n], 0, 0, 0);
        }

        // keep warm loads alive (prevent DCE; rule 17)
        asm volatile("" : : "v"(wv0), "v"(wv1), "v"(wv2), "v"(wv3));

        // ---- ReLU + pack + h -> hl[p] (b64: 4 consecutive hidden dims) ----
        __bf16* hp = &hl[p][0];
#pragma unroll
        for (int m = 0; m < 2; ++m)
#pragma unroll
            for (int n = 0; n < 4; ++n) {
                f32x4 v = acc[m][n];
                bf16x4 h4;
#pragma unroll
                for (int r = 0; r < 4; ++r) {
                    float x = v[r];
                    h4[r] = (__bf16)(x > 0.f ? x : 0.f);
                }
                const int hid = wb + m * 16 + 4 * g;       // 4-aligned
                *(bf16x4*)&hp[swz(n * 16 + l15, hid >> 3) + (hid & 7)] = h4;
            }

        // ---- acc2 init: b2 + fp32 residual direct from global ----
        f32x4 acc2[2][4];
#pragma unroll
        for (int n = 0; n < 4; ++n) {
            const size_t rb = (wid == 3) ? (size_t)bt[n] * 32
                                         : (size_t)(e0 + n * 16 + l15) * 32;
#pragma unroll
            for (int m = 0; m < 2; ++m) {
                f32x4 rx = *(const f32x4*)&rp[rb + m * 16 + 4 * g];
                f32x4 t;
#pragma unroll
                for (int r = 0; r < 4; ++r)
                    t[r] = b2v[m][r] + rx[r];
                acc2[m][n] = t;
            }
        }
        __syncthreads();   // hl[p] writes visible; one barrier per tile

        // ---- GEMM2^T: out^T += W2^T @ h^T ----
#pragma unroll
        for (int ks = 0; ks < 4; ++ks) {
            bf16x8 bh[4];
#pragma unroll
            for (int n = 0; n < 4; ++n)
                bh[n] = *(const bf16x8*)&hp[swz(n * 16 + l15, ks * 4 + g)];
#pragma unroll
            for (int m = 0; m < 2; ++m)
#pragma unroll
                for (int n = 0; n < 4; ++n)
                    acc2[m][n] = __builtin_amdgcn_mfma_f32_16x16x32_bf16(
                        w2t[m][ks], bh[n], acc2[m][n], 0, 0, 0);
        }

        // ---- epilogue: plain float4 stores (4 consecutive out dims) ----
#pragma unroll
        for (int n = 0; n < 4; ++n) {
            const size_t rowbase = (size_t)(e0 + n * 16 + l15) * 128;
#pragma unroll
            for (int m = 0; m < 2; ++m)
                *(f32x4*)&gout[rowbase + wb + m * 16 + g * 4] = acc2[m][n];
        }

        if (!have) break;
        tile = nxt;
        p ^= 1;
    }
}

extern "C" void kernel_launch(void* const* d_in, const int* in_sizes, int n_in,
                              void* d_out, int out_size, void* d_ws, size_t ws_size,
                              hipStream_t stream) {
    const float* src = (const float*)d_in[0];
    const float* dst = (const float*)d_in[1];
    const float* ea  = (const float*)d_in[2];
    const float* u   = (const float*)d_in[3];
    const int*   bt  = (const int*)d_in[4];
    const float* w1  = (const float*)d_in[5];
    const float* b1  = (const float*)d_in[6];
    const float* w2  = (const float*)d_in[7];
    const float* b2  = (const float*)d_in[8];
    float* out = (float*)d_out;

    edge_mlp<<<GRID, 256, 0, stream>>>(src, dst, ea, u, bt, w1, b1, w2, b2, out);
}